// Round 4
// baseline (61.544 us; speedup 1.0000x reference)
//
#include <hip/hip_runtime.h>

#define RCR 5.2f
#define RCA 3.5f
#define PI_F 3.14159265358979323846f

// 512 blocks (two central atoms per block), 512 threads = 8 waves.
//   Waves 0-3 own center i0 = 2*ip, waves 4-7 own center i1 = 2*ip+1 (same
//   molecule c, so neighbor coords/species loads are shared via L1).
//   Per center: identical structure to the R2 kernel —
//     Phase 0: lane = neighbor; wave ww==0 of the group writes float4-packed
//              compacted LDS tables; pairs decoded analytically (no pair list).
//     Radial:  lane owns slot (s = l>>4, shell = l&15); m-loop split across
//              the group's 4 waves; partials in raccs4, summed in epilogue.
//     Angular: 16 pairs in flight per iter (8 pair-slots x 2-body ILP;
//              32 lanes per pair, one (shell,angle) slot per lane).
__global__ __launch_bounds__(512)
void aev_kernel(const int* __restrict__ species,
                const float* __restrict__ coords,
                float* __restrict__ out)
{
    const int blk = blockIdx.x;     // c*32 + ip
    const int c   = blk >> 5;
    const int ip  = blk & 31;
    const int tid = threadIdx.x;    // 0..511
    const int l   = tid & 63;       // lane == neighbor index
    const int w   = tid >> 6;       // wave 0..7
    const int ci  = w >> 2;         // center slot within block (0/1)
    const int ww  = w & 3;          // wave within center group
    const int i   = ip * 2 + ci;    // central atom 0..63
    const int th  = tid & 255;      // thread within center group

    // ---- per-neighbor data in registers (all waves of the group, identical) ----
    const int gbase = (c * 64 + l) * 3;
    float x = coords[gbase + 0];
    float y = coords[gbase + 1];
    float z = coords[gbase + 2];
    int  sp = species[c * 64 + l];

    float xi = __shfl(x, i);        // i is wave-uniform
    float yi = __shfl(y, i);
    float zi = __shfl(z, i);

    float rx = xi - x, ry = yi - y, rz = zi - z;
    float d  = sqrtf(rx * rx + ry * ry + rz * rz);
    bool valid  = (l != i) && (sp != -1);
    bool rvalid = valid && (d <= RCR);
    bool avalid = valid && (d <= RCA);

    __shared__ float4 ang0[2][64];   // rx, ry, rz, d
    __shared__ float4 ang1[2][64];   // 1/d, fc_a, species(bits), 0
    __shared__ float4 radf[2][64];   // d, fc_r, species(bits), 0
    __shared__ float  acc[2][320];
    __shared__ float  raccs4[2][4][64];

    for (int t = th; t < 320; t += 256) acc[ci][t] = 0.f;

    unsigned long long rmask = __ballot(rvalid);   // per-wave = per-center
    unsigned long long amask = __ballot(avalid);
    const int nr = __popcll(rmask);
    const int n  = __popcll(amask);

    if (ww == 0) {
        const unsigned long long below = (l == 0) ? 0ull : (~0ull >> (64 - l));
        if (rvalid) {
            int pos = __popcll(rmask & below);
            radf[ci][pos] = make_float4(d,
                                        0.5f * __cosf(PI_F * d * (1.0f / RCR)) + 0.5f,
                                        __int_as_float(sp), 0.f);
        }
        if (avalid) {
            int pos = __popcll(amask & below);
            ang0[ci][pos] = make_float4(rx, ry, rz, d);
            ang1[ci][pos] = make_float4(1.0f / fmaxf(d, 1e-8f),
                                        0.5f * __cosf(PI_F * d * (1.0f / RCA)) + 0.5f,
                                        __int_as_float(sp), 0.f);
        }
    }
    __syncthreads();

    // ---- radial: lane l owns slot (s = l>>4, shell = l&15); m split by ww ----
    const int   s   = l >> 4;
    const float shf = 0.9f + 0.26875f * (float)(l & 15);
    float racc = 0.f;
    for (int m = ww; m < nr; m += 4) {
        float4 rv   = radf[ci][m];
        float  dd   = rv.x - shf;
        float  term = 0.25f * __expf(-16.f * dd * dd) * rv.y;
        racc += (__float_as_int(rv.z) == s) ? term : 0.f;
    }
    raccs4[ci][ww][l] = racc;

    // ---- angular: analytic pair decode; 2 pairs per half-wave per iter ----
    const int   sub  = l & 31;                       // aa*8 + z
    const float shfa = 0.9f + 0.65f * (float)(sub >> 3);
    const float shfz = PI_F / 16.f + (PI_F / 8.f) * (float)(sub & 7);
    const float czv  = __cosf(shfz);
    const float szv  = __sinf(shfz);
    const int   np   = (n * (n - 1)) >> 1;
    const int   lane_pair = (ww << 1) + (l >> 5);    // 0..7 within the group

    auto do_pair = [&](int p) {
        if (p < np) {
            // invert triangular index (rows a ascending with n-1-a entries)
            int rev = np - 1 - p;
            int k = (int)floorf((sqrtf((float)(8 * rev + 1)) - 1.0f) * 0.5f);
            int tk = (k * (k + 1)) >> 1;
            if (tk > rev)                             { --k; tk = (k * (k + 1)) >> 1; }
            else if (((k + 1) * (k + 2)) >> 1 <= rev) { ++k; tk = (k * (k + 1)) >> 1; }
            const int a = n - 2 - k;
            const int b = n - 1 - (rev - tk);

            float4 A0 = ang0[ci][a], A1 = ang1[ci][a];
            float4 B0 = ang0[ci][b], B1 = ang1[ci][b];
            float dot = A0.x * B0.x + A0.y * B0.y + A0.z * B0.z;
            float ca  = 0.95f * dot * A1.x * B1.x;
            float sa  = sqrtf(fmaxf(0.f, 1.f - ca * ca));
            float dm  = 0.5f * (A0.w + B0.w);
            float fprod = 2.f * A1.y * B1.y;
            int s1 = __float_as_int(A1.z), s2 = __float_as_int(B1.z);
            int mn = min(s1, s2), mx = max(s1, s2);
            int pid = ((mn * (7 - mn)) >> 1) + mx;
            float cdz = ca * czv + sa * szv;
            float t = 0.5f + 0.5f * cdz;
            t = t * t; t = t * t; t = t * t; t = t * t; t = t * t;  // ^32
            float u = dm - shfa;
            float val = t * __expf(-8.f * u * u) * fprod;
            atomicAdd(&acc[ci][pid * 32 + sub], val);
        }
    };

    for (int p0 = 0; p0 < np; p0 += 16) {
        do_pair(p0 + lane_pair);          // two independent pair bodies
        do_pair(p0 + 8 + lane_pair);      // interleaved for ILP
    }
    __syncthreads();

    // ---- epilogue: each 256-thread group writes its center's 384 floats ----
    const long ob = (long)(c * 64 + i) * 384;
    if (th < 64)
        out[ob + th] = raccs4[ci][0][th] + raccs4[ci][1][th]
                     + raccs4[ci][2][th] + raccs4[ci][3][th];
    for (int t = th; t < 320; t += 256) out[ob + 64 + t] = acc[ci][t];
}

extern "C" void kernel_launch(void* const* d_in, const int* in_sizes, int n_in,
                              void* d_out, int out_size, void* d_ws, size_t ws_size,
                              hipStream_t stream) {
    const int* species  = (const int*)d_in[0];
    const float* coords = (const float*)d_in[1];
    float* out          = (float*)d_out;
    aev_kernel<<<dim3(16 * 32), dim3(512), 0, stream>>>(species, coords, out);
}